// Round 1
// baseline (234.470 us; speedup 1.0000x reference)
//
#include <hip/hip_runtime.h>
#include <hip/hip_bf16.h>

#define NVEC   262144
#define NLIST  1024
#define DIM    64
#define NCHUNK 64          // 64 chunks x 16 centroids
#define SCALE  4096.0f     // int score quantum = 1/4096
#define DELTA_INT 32       // gap threshold in quanta (7.8e-3 in d^2, ~4x worst err)

typedef __attribute__((ext_vector_type(8))) short bf16x8;
typedef __attribute__((ext_vector_type(4))) float f32x4;

__device__ __forceinline__ unsigned short bf_rne(float f) {
    unsigned int u = __float_as_uint(f);
    u += 0x7fffu + ((u >> 16) & 1u);
    return (unsigned short)(u >> 16);
}
__device__ __forceinline__ float bf_up(unsigned short s) {
    return __uint_as_float(((unsigned int)s) << 16);
}

// ---------------------------------------------------------------------------
// K0: csq + csq*SCALE (exact fp32), zero counter, build cmat in FRAG ORDER:
// chunk ch = 4KB image [read r 0..3][lane l][8 shorts]:
//   r=0: hi k 0..31   r=1: hi k 32..63   r=2: lo k 0..31   r=3: lo k 32..63
// assign reads fragment r for chunk ch at cmat + ch*2048 + r*512 + lane*8
// (shorts) -> one base VGPR pair + offset:{0,1024,2048,3072} immediates.
// ---------------------------------------------------------------------------
__global__ __launch_bounds__(256) void prep_kernel(const float* __restrict__ cents,
                                                   float* __restrict__ csq,
                                                   float* __restrict__ csq4k,
                                                   int* __restrict__ counter,
                                                   unsigned short* __restrict__ cmat) {
    int gid = blockIdx.x * 256 + threadIdx.x;     // 0..16383
    if (gid == 0) *counter = 0;
    if (gid < NLIST) {
        const float4* p = (const float4*)(cents + (size_t)gid * DIM);
        float s = 0.f;
#pragma unroll
        for (int i = 0; i < DIM / 4; ++i) {
            float4 t = p[i];
            s += t.x * t.x + t.y * t.y + t.z * t.z + t.w * t.w;
        }
        csq[gid] = s;
        csq4k[gid] = s * SCALE;
    }
    int c   = gid >> 4;        // centroid 0..1023
    int sub = gid & 15;        // r*4 + q
    int r   = sub >> 2;
    int qq  = sub & 3;
    const float* src = cents + (size_t)c * DIM + (r & 1) * 32 + qq * 8;
    unsigned short* dst = cmat + (c >> 4) * 2048 + r * 512 + (qq * 16 + (c & 15)) * 8;
    bool hi = (r < 2);
#pragma unroll
    for (int i = 0; i < 8; ++i) {
        float v = src[i];
        unsigned short h = bf_rne(v);
        dst[i] = hi ? h : bf_rne(v - bf_up(h));
    }
}

// ---------------------------------------------------------------------------
// K1: MFMA assign + fused gather. NO LDS staging: cmat (256 KB) is L2-resident
// and identical across all waves -> A-fragments read directly via broadcast
// global_load_dwordx4 (base + imm offsets). Zero barriers in the main loop.
// 4 waves/block, 4 tiles/wave (64 vecs/wave, 256 vecs/block), grid 1024 =
// exactly 4 blocks/CU (single uniform residency pass, VGPR cap 128).
// dot = c_hi.x_hi + c_lo.x_hi + c_hi.x_lo   (verified math)
// Scores as ints: e = (trunc(SCALE*d2)<<10)|cent -> top-2 via min/max i32.
// ---------------------------------------------------------------------------
__global__ __launch_bounds__(256, 4) void assign_mfma(const float* __restrict__ vecs,
                                                      const float* __restrict__ cents,
                                                      const unsigned short* __restrict__ cmat,
                                                      const float* __restrict__ csq4k,
                                                      float* __restrict__ out,
                                                      int* __restrict__ counter,
                                                      int* __restrict__ list) {
    __shared__ unsigned short widx[256];                            // 512 B

    const int tid  = threadIdx.x;
    const int lane = tid & 63;
    const int wave = tid >> 6;
    const int n    = lane & 15;   // vec-in-tile (B / D-col), cent (A-row)
    const int q    = lane >> 4;   // k-group; D-row group

    const int vbase = blockIdx.x * 256 + wave * 64;

    // B fragments: x_hi/x_lo, 2 K-blocks of 32, 4 tiles. 64 VGPRs persistent.
    bf16x8 xhi[4][2], xlo[4][2];
#pragma unroll
    for (int t = 0; t < 4; ++t) {
        const float* vp = vecs + (size_t)(vbase + t * 16 + n) * DIM + q * 8;
#pragma unroll
        for (int kb = 0; kb < 2; ++kb) {
            float4 f0 = *(const float4*)(vp + kb * 32);
            float4 f1 = *(const float4*)(vp + kb * 32 + 4);
            float vv[8] = {f0.x, f0.y, f0.z, f0.w, f1.x, f1.y, f1.z, f1.w};
#pragma unroll
            for (int i = 0; i < 8; ++i) {
                unsigned short h = bf_rne(vv[i]);
                xhi[t][kb][i] = (short)h;
                xlo[t][kb][i] = (short)bf_rne(vv[i] - bf_up(h));
            }
        }
    }

    const int IMAX = 0x7FFFFFFF;
    int min1[4] = {IMAX, IMAX, IMAX, IMAX};
    int min2[4] = {IMAX, IMAX, IMAX, IMAX};

    const unsigned short* ap = cmat + lane * 8;   // +2048 shorts (4 KB) per chunk
    const float* cp = csq4k + q * 4;              // +16 floats per chunk

#pragma unroll 2
    for (int c = 0; c < NCHUNK; ++c) {
        bf16x8 a0 = *(const bf16x8*)(ap);          // hi, k 0..31
        bf16x8 a1 = *(const bf16x8*)(ap + 512);    // hi, k 32..63
        bf16x8 a2 = *(const bf16x8*)(ap + 1024);   // lo, k 0..31
        bf16x8 a3 = *(const bf16x8*)(ap + 1536);   // lo, k 32..63
        float4 cs = *(const float4*)(cp);

        f32x4 acc[4];
#pragma unroll
        for (int t = 0; t < 4; ++t) acc[t] = (f32x4){0.f, 0.f, 0.f, 0.f};

        // dot = c_hi.x_hi + c_lo.x_hi + c_hi.x_lo
        __builtin_amdgcn_s_setprio(1);
#pragma unroll
        for (int t = 0; t < 4; ++t) acc[t] = __builtin_amdgcn_mfma_f32_16x16x32_bf16(a0, xhi[t][0], acc[t], 0, 0, 0);
#pragma unroll
        for (int t = 0; t < 4; ++t) acc[t] = __builtin_amdgcn_mfma_f32_16x16x32_bf16(a1, xhi[t][1], acc[t], 0, 0, 0);
#pragma unroll
        for (int t = 0; t < 4; ++t) acc[t] = __builtin_amdgcn_mfma_f32_16x16x32_bf16(a2, xhi[t][0], acc[t], 0, 0, 0);
#pragma unroll
        for (int t = 0; t < 4; ++t) acc[t] = __builtin_amdgcn_mfma_f32_16x16x32_bf16(a3, xhi[t][1], acc[t], 0, 0, 0);
#pragma unroll
        for (int t = 0; t < 4; ++t) acc[t] = __builtin_amdgcn_mfma_f32_16x16x32_bf16(a0, xlo[t][0], acc[t], 0, 0, 0);
#pragma unroll
        for (int t = 0; t < 4; ++t) acc[t] = __builtin_amdgcn_mfma_f32_16x16x32_bf16(a1, xlo[t][1], acc[t], 0, 0, 0);
        __builtin_amdgcn_s_setprio(0);

        const int bg = c * 16 + q * 4;      // + r = centroid index (10 bits)
        float csr[4] = {cs.x, cs.y, cs.z, cs.w};
#pragma unroll
        for (int t = 0; t < 4; ++t) {
#pragma unroll
            for (int r = 0; r < 4; ++r) {
                float s = fmaf(-2.0f * SCALE, acc[t][r], csr[r]);
                int qi = (int)s;            // trunc, monotone
                int e = (int)((((unsigned)qi) << 10) | (unsigned)(bg + r));
                min2[t] = min(min2[t], max(min1[t], e));   // old min1!
                min1[t] = min(min1[t], e);
            }
        }
        ap += 2048;
        cp += 16;
    }

    // merge top-2 across the 4 quads of each vec-column
#pragma unroll
    for (int t = 0; t < 4; ++t) {
#pragma unroll
        for (int off = 16; off <= 32; off <<= 1) {
            int o1 = __shfl_xor(min1[t], off, 64);
            int o2 = __shfl_xor(min2[t], off, 64);
            int nm2 = min(max(min1[t], o1), min(min2[t], o2));
            min1[t] = min(min1[t], o1);
            min2[t] = nm2;
        }
        if (lane < 16) {
            int slot = wave * 64 + t * 16 + lane;
            widx[slot] = (unsigned short)(min1[t] & 1023);
            if ((min2[t] >> 10) - (min1[t] >> 10) < DELTA_INT) {
                int pos = atomicAdd(counter, 1);
                list[pos] = blockIdx.x * 256 + slot;
            }
        }
    }

    __syncthreads();
    // fused gather: 256 rows x 64 floats, fully coalesced float4 stores
    const size_t obase = (size_t)blockIdx.x * 256;
#pragma unroll
    for (int gI = 0; gI < 16; ++gI) {
        int row = gI * 16 + (tid >> 4);
        int e = tid & 15;
        int idx = widx[row];
        ((float4*)out)[(obase + row) * 16 + e] =
            ((const float4*)cents)[(size_t)idx * 16 + e];
    }
}

// ---------------------------------------------------------------------------
// K2: exact fp32 rescue — block per PAIR of flagged rows; 256 threads,
// thread t dots centroids {t, 256+t, 512+t, 768+t} for both rows (cent row
// loaded once). Exact round-0 fmaf chain; lexicographic (s, idx) reduction.
// ---------------------------------------------------------------------------
__global__ __launch_bounds__(256) void rescue_kernel(const float* __restrict__ vecs,
                                                     const float* __restrict__ cents,
                                                     const float* __restrict__ csq,
                                                     const int* __restrict__ counter,
                                                     const int* __restrict__ list,
                                                     float* __restrict__ out) {
    __shared__ __align__(16) float xs[2][DIM];
    __shared__ float rbest[8];
    __shared__ int   rbi[8];
    __shared__ int   fin[2];

    const int nflag = *counter;
    const int tid  = threadIdx.x;
    const int lane = tid & 63;
    const int wv   = tid >> 6;

    for (int i = blockIdx.x * 2; i < nflag; i += gridDim.x * 2) {
        int v0 = list[i];
        int v1 = (i + 1 < nflag) ? list[i + 1] : v0;
        __syncthreads();
        if (tid < 16)       ((float4*)xs[0])[tid]      = ((const float4*)(vecs + (size_t)v0 * DIM))[tid];
        else if (tid < 32)  ((float4*)xs[1])[tid - 16] = ((const float4*)(vecs + (size_t)v1 * DIM))[tid - 16];
        __syncthreads();

        float b0 = 3.0e38f, b1 = 3.0e38f;
        int   i0 = 0, i1 = 0;
#pragma unroll
        for (int j = 0; j < 4; ++j) {
            int c = j * 256 + tid;              // ascending per thread
            const float4* cp = (const float4*)(cents + (size_t)c * DIM);
            float a0 = 0.f, a1 = 0.f, a2 = 0.f, a3 = 0.f;
            float c0 = 0.f, c1 = 0.f, c2 = 0.f, c3 = 0.f;
#pragma unroll
            for (int k = 0; k < DIM / 4; ++k) {
                float4 cv = cp[k];
                float4 x0 = ((const float4*)xs[0])[k];
                float4 x1 = ((const float4*)xs[1])[k];
                a0 = fmaf(x0.x, cv.x, a0);
                a1 = fmaf(x0.y, cv.y, a1);
                a2 = fmaf(x0.z, cv.z, a2);
                a3 = fmaf(x0.w, cv.w, a3);
                c0 = fmaf(x1.x, cv.x, c0);
                c1 = fmaf(x1.y, cv.y, c1);
                c2 = fmaf(x1.z, cv.z, c2);
                c3 = fmaf(x1.w, cv.w, c3);
            }
            float d0 = (a0 + a1) + (a2 + a3);
            float d1 = (c0 + c1) + (c2 + c3);
            float s0 = fmaf(-2.f, d0, csq[c]);
            float s1 = fmaf(-2.f, d1, csq[c]);
            if (s0 < b0) { b0 = s0; i0 = c; }
            if (s1 < b1) { b1 = s1; i1 = c; }
        }
        // wave-level lexicographic (s, idx) argmin
#pragma unroll
        for (int off = 1; off < 64; off <<= 1) {
            float os = __shfl_xor(b0, off, 64);
            int   oi = __shfl_xor(i0, off, 64);
            if (os < b0 || (os == b0 && oi < i0)) { b0 = os; i0 = oi; }
            float ps = __shfl_xor(b1, off, 64);
            int   pi = __shfl_xor(i1, off, 64);
            if (ps < b1 || (ps == b1 && pi < i1)) { b1 = ps; i1 = pi; }
        }
        if (lane == 0) {
            rbest[wv] = b0;     rbi[wv] = i0;
            rbest[wv + 4] = b1; rbi[wv + 4] = i1;
        }
        __syncthreads();
        if (tid < 2) {
            float bb = rbest[tid * 4 + 0]; int bi = rbi[tid * 4 + 0];
#pragma unroll
            for (int w = 1; w < 4; ++w) {
                float s = rbest[tid * 4 + w]; int ix = rbi[tid * 4 + w];
                if (s < bb || (s == bb && ix < bi)) { bb = s; bi = ix; }
            }
            fin[tid] = bi;
        }
        __syncthreads();
        int bi0 = fin[0], bi1 = fin[1];
        if (tid < 16)
            ((float4*)(out + (size_t)v0 * DIM))[tid] =
                ((const float4*)(cents + (size_t)bi0 * DIM))[tid];
        else if (tid < 32)
            ((float4*)(out + (size_t)v1 * DIM))[tid - 16] =
                ((const float4*)(cents + (size_t)bi1 * DIM))[tid - 16];
    }
}

extern "C" void kernel_launch(void* const* d_in, const int* in_sizes, int n_in,
                              void* d_out, int out_size, void* d_ws, size_t ws_size,
                              hipStream_t stream) {
    const float* vecs  = (const float*)d_in[0];
    const float* cents = (const float*)d_in[1];
    float*       out   = (float*)d_out;

    // ws layout (16B aligned)
    float*          csq     = (float*)d_ws;                                     //   4096 B
    float*          csq4k   = (float*)((char*)d_ws + 4096);                     //   4096 B
    int*            counter = (int*)((char*)d_ws + 8192);                       //    256 B
    int*            list    = (int*)((char*)d_ws + 16384);                      //   1 MB
    unsigned short* cmat    = (unsigned short*)((char*)d_ws + 16384 + 1048576); // 256 KB

    prep_kernel<<<dim3(64), dim3(256), 0, stream>>>(cents, csq, csq4k, counter, cmat);
    assign_mfma<<<dim3(1024), dim3(256), 0, stream>>>(vecs, cents, cmat, csq4k, out, counter, list);
    rescue_kernel<<<dim3(2048), dim3(256), 0, stream>>>(vecs, cents, csq, counter, list, out);
}